// Round 3
// baseline (382.891 us; speedup 1.0000x reference)
//
#include <hip/hip_runtime.h>
#include <stdint.h>

#define N_NODES 50000
#define N_EDGES 800000
#define EMB 128
#define NPAD 50176        // padded to multiple of 128 rows for MLP (392 blocks x 128)
#define MBLK 392          // NPAD / 128
#define BN_EPS 1e-5f
#define SENT_KEY ((N_NODES << 5) | 21)   // sentinel: zero h-row, zero e12 entry
#define NODES_PER_XCD 6250               // 50000 / 8
#define XCHUNK 2048
#define NCHUNKS ((N_EDGES + XCHUNK - 1) / XCHUNK)   // 391
#define PBLK 196                          // ceil(N_NODES/256) blocks doing perm build

typedef __attribute__((ext_vector_type(8))) short short8;
typedef __attribute__((ext_vector_type(4))) float f32x4;

__device__ __forceinline__ unsigned short f2bf(float f) {
    unsigned int u = __float_as_uint(f);
    u += 0x7fffu + ((u >> 16) & 1u);   // RNE; values finite
    return (unsigned short)(u >> 16);
}
__device__ __forceinline__ float bflo(unsigned int v) { return __uint_as_float(v << 16); }
__device__ __forceinline__ float bfhi(unsigned int v) { return __uint_as_float(v & 0xffff0000u); }
__device__ __forceinline__ unsigned int packbf(float lo, float hi) {
    return (unsigned int)f2bf(lo) | ((unsigned int)f2bf(hi) << 16);
}

// ------- fused prep: embedding + zero(deg/bn/buckets) + weight transpose/cast + key precompute -------
__global__ void k_prep(const int* __restrict__ x, const float* __restrict__ xe1,
                       const float* __restrict__ xe2, unsigned int* __restrict__ h,
                       const float* __restrict__ W1, const float* __restrict__ W2,
                       unsigned short* __restrict__ w1t, unsigned short* __restrict__ w2t,
                       int* __restrict__ deg,
                       const int* __restrict__ ei, const int* __restrict__ ea,
                       int* __restrict__ keyv, float* __restrict__ bnsum,
                       int* __restrict__ bmeta) {
    int idx = blockIdx.x * 256 + threadIdx.x;   // [0, (N+1)*64)
    int i = idx >> 6, j = idx & 63;
    if (i < N_NODES) {
        int a = x[2 * i], c = x[2 * i + 1];
        float2 va = *(const float2*)(xe1 + a * EMB + j * 2);
        float2 vb = *(const float2*)(xe2 + c * EMB + j * 2);
        h[i * 64 + j] = packbf(va.x + vb.x, va.y + vb.y);
    } else if (i == N_NODES) {
        h[(size_t)i * 64 + j] = 0u;             // zero sentinel row
    }
    if (idx < 4 * 32768) {                      // weight transpose+cast
        int sec = idx >> 15, q = idx & 32767;
        if (sec < 2) {       // W1[sec]: [128][256] -> w1t[sec][c*128+r]
            int r = q >> 8, c = q & 255;
            w1t[sec * 32768 + c * 128 + r] = f2bf(W1[sec * 32768 + q]);
        } else {             // W2[sec-2]: [256][128] -> w2t[sec-2][c*256+r]
            int s = sec - 2;
            int r = q >> 7, c = q & 127;
            w2t[s * 32768 + c * 256 + r] = f2bf(W2[s * 32768 + q]);
        }
    }
    if (idx < N_EDGES) {                        // packed key precompute
        int2 aa = *(const int2*)(ea + 2 * idx);
        keyv[idx] = (ei[idx] << 5) | (aa.x * 3 + aa.y);
    }
    if (idx < N_NODES) deg[idx] = 0;
    if (idx < 512) bnsum[idx] = 0.f;            // [2][256] BN accumulators
    if (idx < 16) bmeta[idx] = 0;               // bcnt[8] + bcur[8]
}

// ---------------- CSR build (padded-to-16 per node), XCD-partitioned -------------
__global__ void k_hist(const int* __restrict__ dst, int* __restrict__ deg) {
    int xcd = blockIdx.x & 7, chunk = blockIdx.x >> 3;
    int lo = xcd * NODES_PER_XCD, hi = lo + NODES_PER_XCD;
    int e0 = chunk * XCHUNK + threadIdx.x * 4;
#pragma unroll
    for (int it = 0; it < XCHUNK / 1024; ++it) {
        int e = e0 + it * 1024;
        if (e < N_EDGES) {
            int4 d4 = *(const int4*)(dst + e);
            if (d4.x >= lo && d4.x < hi) atomicAdd(&deg[d4.x], 1);
            if (d4.y >= lo && d4.y < hi) atomicAdd(&deg[d4.y], 1);
            if (d4.z >= lo && d4.z < hi) atomicAdd(&deg[d4.z], 1);
            if (d4.w >= lo && d4.w < hi) atomicAdd(&deg[d4.w], 1);
        }
    }
}

// scan over PADDED degrees (pdeg=ceil(deg/16)*16) — shfl-based, 2 barriers
__global__ void k_scan1(const int* __restrict__ deg, int* __restrict__ part, int* __restrict__ bsums) {
    __shared__ int wsum[16];
    int lane = threadIdx.x & 63, wid = threadIdx.x >> 6;
    int i = blockIdx.x * 1024 + threadIdx.x;
    int d = (i < N_NODES) ? deg[i] : 0;
    int v = (d + 15) & ~15;
    int s = v;
#pragma unroll
    for (int off = 1; off < 64; off <<= 1) {
        int t = __shfl_up(s, off);
        if (lane >= off) s += t;
    }
    if (lane == 63) wsum[wid] = s;
    __syncthreads();
    if (wid == 0) {
        int w = (lane < 16) ? wsum[lane] : 0;
#pragma unroll
        for (int off = 1; off < 16; off <<= 1) {
            int t = __shfl_up(w, off);
            if (lane >= off) w += t;
        }
        if (lane < 16) wsum[lane] = w;   // inclusive wave-sum scan
    }
    __syncthreads();
    int base = (wid > 0) ? wsum[wid - 1] : 0;
    if (i < N_NODES) part[i] = base + s - v;   // exclusive within block
    if (threadIdx.x == 1023) bsums[blockIdx.x] = wsum[15];
}

// scan finalize + sentinel padding + per-block bucket counts (for degree sort)
__global__ void k_scan3(const int* __restrict__ part, const int* __restrict__ bsums,
                        const int* __restrict__ deg, int* __restrict__ offs,
                        int* __restrict__ cursor, int* __restrict__ keys,
                        int* __restrict__ bcnt) {
    __shared__ int bs[64];
    __shared__ int lc[8];
    int tid = threadIdx.x;
    if (tid < 8) lc[tid] = 0;
    if (tid < 64) {                       // wave 0 scans the 49 block sums (exclusive)
        int v = (tid < 49) ? bsums[tid] : 0;
        int orig = v;
#pragma unroll
        for (int off = 1; off < 64; off <<= 1) {
            int t = __shfl_up(v, off);
            if (tid >= off) v += t;
        }
        bs[tid] = v - orig;
    }
    __syncthreads();
    int i = blockIdx.x * 256 + tid;
    if (i < N_NODES) {
        int o = part[i] + bs[i >> 10];
        offs[i] = o;
        cursor[i] = o;
        int d = deg[i], pd = (d + 15) & ~15;
        for (int j = d; j < pd; ++j) keys[o + j] = SENT_KEY;
        if (i == N_NODES - 1) offs[N_NODES] = o + pd;
        int nch = pd >> 4;
        atomicAdd(&lc[nch > 7 ? 7 : nch], 1);
    }
    __syncthreads();
    if (tid < 8) atomicAdd(&bcnt[tid], lc[tid]);
}

// fill packed keys via keyv gather (XCD-partitioned) + build degree-bucket permutation
__global__ void k_fill(const int* __restrict__ dst, const int* __restrict__ keyv,
                       int* __restrict__ cursor, int* __restrict__ keys,
                       const int* __restrict__ deg, const int* __restrict__ bcnt,
                       int* __restrict__ bcur, int* __restrict__ perm) {
    int xcd = blockIdx.x & 7, chunk = blockIdx.x >> 3;
    int lo = xcd * NODES_PER_XCD, hi = lo + NODES_PER_XCD;
    int e0 = chunk * XCHUNK + threadIdx.x * 4;
#pragma unroll
    for (int it = 0; it < XCHUNK / 1024; ++it) {
        int e = e0 + it * 1024;
        if (e < N_EDGES) {
            int4 d4 = *(const int4*)(dst + e);
            int dv[4] = {d4.x, d4.y, d4.z, d4.w};
#pragma unroll
            for (int q = 0; q < 4; ++q) {
                int d = dv[q];
                if (d >= lo && d < hi) {
                    int p = atomicAdd(&cursor[d], 1);
                    keys[p] = keyv[e + q];
                }
            }
        }
    }
    // degree-bucket counting sort: first PBLK blocks place their 256 nodes
    if (blockIdx.x < PBLK) {
        __shared__ int lcnt[8], gbase[8], tbase[8];
        if (threadIdx.x < 8) lcnt[threadIdx.x] = 0;
        __syncthreads();
        int i = blockIdx.x * 256 + threadIdx.x;
        int b = 0, lrank = 0;
        if (i < N_NODES) {
            int nch = (deg[i] + 15) >> 4;
            b = nch > 7 ? 7 : nch;
            lrank = atomicAdd(&lcnt[b], 1);
        }
        __syncthreads();
        if (threadIdx.x < 8) {
            gbase[threadIdx.x] = atomicAdd(&bcur[threadIdx.x], lcnt[threadIdx.x]);
            int s = 0;
            for (int k = 0; k < threadIdx.x; ++k) s += bcnt[k];
            tbase[threadIdx.x] = s;
        }
        __syncthreads();
        if (i < N_NODES) perm[tbase[b] + gbase[b] + lrank] = i;
    }
}

// ---------------- aggregation: one node per 16-lane group, degree-sorted slots -------------
// Wave's 4 nodes come from the same degree bucket -> wave-max chunk padding ~eliminated.
__global__ __launch_bounds__(256) void k_agg(
    const unsigned int* __restrict__ h,        // [(N+1)][64] packed bf16x2 (row N = zeros)
    const int* __restrict__ offs,              // [N+1] padded offsets
    const int* __restrict__ keys,              // padded packed keys
    const int* __restrict__ perm,              // degree-bucket-sorted node ids
    const float* __restrict__ e1l, const float* __restrict__ e2l,
    unsigned int* __restrict__ agg)            // [NPAD][64] packed bf16x2
{
    __shared__ float e12[22 * 132];            // stride 132 staggers rows across banks
    for (int t = threadIdx.x; t < 22 * 128; t += 256) {
        int combo = t >> 7, f = t & 127;
        float v = 0.f;
        if (combo < 21) {
            int a0 = combo / 3, a1 = combo - a0 * 3;
            v = e1l[a0 * EMB + f] + e2l[a1 * EMB + f];
        }
        e12[combo * 132 + f] = v;
    }
    __syncthreads();
    int wave = threadIdx.x >> 6, lane = threadIdx.x & 63;
    int sub = lane >> 4, fl = lane & 15;
    int slot = blockIdx.x * 16 + wave * 4 + sub;
    int node = (slot < N_NODES) ? perm[slot] : slot;
    float ax[8] = {0.f, 0.f, 0.f, 0.f, 0.f, 0.f, 0.f, 0.f};
    int o = 0, nch = 0;
    if (node < N_NODES) {
        o = offs[node];
        nch = (offs[node + 1] - o) >> 4;
        // self loop: attr=[4,0] -> combo 12
        uint4 hv = *(const uint4*)(h + (size_t)node * 64 + fl * 4);
        const float* ep = e12 + 12 * 132 + fl * 8;
        float4 e0 = *(const float4*)ep, e1_ = *(const float4*)(ep + 4);
        ax[0] = bflo(hv.x) + e0.x;  ax[1] = bfhi(hv.x) + e0.y;
        ax[2] = bflo(hv.y) + e0.z;  ax[3] = bfhi(hv.y) + e0.w;
        ax[4] = bflo(hv.z) + e1_.x; ax[5] = bfhi(hv.z) + e1_.y;
        ax[6] = bflo(hv.w) + e1_.z; ax[7] = bfhi(hv.w) + e1_.w;
    }
    int maxch = nch;
#pragma unroll
    for (int d = 32; d; d >>= 1) maxch = max(maxch, __shfl_xor(maxch, d));
    int key = (0 < nch) ? keys[o + fl] : SENT_KEY;
    for (int c = 0; c < maxch; ++c) {
        int keyn = (c + 1 < nch) ? keys[o + (c + 1) * 16 + fl] : SENT_KEY;
#pragma unroll
        for (int j = 0; j < 16; ++j) {
            int kj = __shfl(key, sub * 16 + j);
            uint4 g = *(const uint4*)(h + (size_t)(kj >> 5) * 64 + fl * 4);
            const float* ep = e12 + (kj & 31) * 132 + fl * 8;
            float4 e0 = *(const float4*)ep, e1_ = *(const float4*)(ep + 4);
            ax[0] += bflo(g.x) + e0.x;  ax[1] += bfhi(g.x) + e0.y;
            ax[2] += bflo(g.y) + e0.z;  ax[3] += bfhi(g.y) + e0.w;
            ax[4] += bflo(g.z) + e1_.x; ax[5] += bfhi(g.z) + e1_.y;
            ax[6] += bflo(g.w) + e1_.z; ax[7] += bfhi(g.w) + e1_.w;
        }
        key = keyn;
    }
    {
        uint4 out;
        out.x = packbf(ax[0], ax[1]); out.y = packbf(ax[2], ax[3]);
        out.z = packbf(ax[4], ax[5]); out.w = packbf(ax[6], ax[7]);
        *(uint4*)(agg + (size_t)node * 64 + fl * 4) = out;   // pad rows -> zeros
    }
}

// ---------------- fused MLP + BN stats: h2 = relu(agg@W1+b1)@W2+b2 ----------------
__global__ __launch_bounds__(256, 2) void k_mlp(
    unsigned short* aggh2,                     // [NPAD][128] bf16 in, [N][128] bf16 out
    const unsigned short* __restrict__ w1t,    // [256][128]  (W1 transposed: [n][k])
    const float* __restrict__ b1,              // [256]
    const unsigned short* __restrict__ w2t,    // [128][256]  (W2 transposed: [n][k])
    const float* __restrict__ b2,              // [128]
    float* __restrict__ bnsum)                 // [256]: cols 0..127 sum, 128..255 sumsq
{
    __shared__ float bn[256];
    int lane = threadIdx.x & 63;
    int wave = threadIdx.x >> 6;
    int quad = lane >> 4, r16 = lane & 15;
    int m0 = (blockIdx.x * 4 + wave) * 32;     // 32 rows per wave
    int sel  = (lane >> 5) & 1;
    int srcA = ((lane >> 4) & 1) * 32 + r16;
    int srcB = srcA + 16;
    bn[threadIdx.x] = 0.f;

    // agg B-frags (GEMM1 swapped): B[k=quad*8+j][node=r16]
    short8 bagg[2][4];
#pragma unroll
    for (int t = 0; t < 2; ++t)
#pragma unroll
        for (int c = 0; c < 4; ++c)
            bagg[t][c] = *(const short8*)(aggh2 + (size_t)(m0 + t * 16 + r16) * 128 + c * 32 + quad * 8);

    float b2v[8];
#pragma unroll
    for (int n = 0; n < 8; ++n) b2v[n] = b2[n * 16 + r16];

    f32x4 acc2[2][8];
#pragma unroll
    for (int t = 0; t < 2; ++t)
#pragma unroll
        for (int n = 0; n < 8; ++n) acc2[t][n] = (f32x4){0.f, 0.f, 0.f, 0.f};

    for (int c2 = 0; c2 < 8; ++c2) {
        unsigned int pk[2][2][2];              // [ntl][tile][dword]
#pragma unroll
        for (int ntl = 0; ntl < 2; ++ntl) {
            int nt = c2 * 2 + ntl;
            short8 aw[4];
#pragma unroll
            for (int c = 0; c < 4; ++c)
                aw[c] = *(const short8*)(w1t + (nt * 16 + r16) * 128 + c * 32 + quad * 8);
            float4 bv = *(const float4*)(b1 + nt * 16 + quad * 4);
#pragma unroll
            for (int t = 0; t < 2; ++t) {
                f32x4 a1 = {0.f, 0.f, 0.f, 0.f};
#pragma unroll
                for (int c = 0; c < 4; ++c)
                    a1 = __builtin_amdgcn_mfma_f32_16x16x32_bf16(aw[c], bagg[t][c], a1, 0, 0, 0);
                float v0 = a1[0] + bv.x; v0 = v0 > 0.f ? v0 : 0.f;
                float v1 = a1[1] + bv.y; v1 = v1 > 0.f ? v1 : 0.f;
                float v2 = a1[2] + bv.z; v2 = v2 > 0.f ? v2 : 0.f;
                float v3 = a1[3] + bv.w; v3 = v3 > 0.f ? v3 : 0.f;
                pk[ntl][t][0] = packbf(v0, v1);
                pk[ntl][t][1] = packbf(v2, v3);
            }
        }
        short8 a2f[2];
#pragma unroll
        for (int t = 0; t < 2; ++t) {
            int u0 = __shfl((int)pk[0][t][0], srcA), w0 = __shfl((int)pk[1][t][0], srcA);
            int u1 = __shfl((int)pk[0][t][1], srcA), w1_ = __shfl((int)pk[1][t][1], srcA);
            int u2 = __shfl((int)pk[0][t][0], srcB), w2_ = __shfl((int)pk[1][t][0], srcB);
            int u3 = __shfl((int)pk[0][t][1], srcB), w3_ = __shfl((int)pk[1][t][1], srcB);
            union { int i[4]; short8 s; } a2u;
            a2u.i[0] = sel ? w0 : u0;
            a2u.i[1] = sel ? w1_ : u1;
            a2u.i[2] = sel ? w2_ : u2;
            a2u.i[3] = sel ? w3_ : u3;
            a2f[t] = a2u.s;
        }
#pragma unroll
        for (int n = 0; n < 8; ++n) {
            short8 bw = *(const short8*)(w2t + (n * 16 + r16) * 256 + c2 * 32 + quad * 8);
            acc2[0][n] = __builtin_amdgcn_mfma_f32_16x16x32_bf16(a2f[0], bw, acc2[0][n], 0, 0, 0);
            acc2[1][n] = __builtin_amdgcn_mfma_f32_16x16x32_bf16(a2f[1], bw, acc2[1][n], 0, 0, 0);
        }
    }
    // epilogue: store h2 + accumulate per-lane BN partial sums (fp32, rows < N only)
    float s[8], q[8];
#pragma unroll
    for (int n = 0; n < 8; ++n) { s[n] = 0.f; q[n] = 0.f; }
#pragma unroll
    for (int t = 0; t < 2; ++t)
#pragma unroll
        for (int n = 0; n < 8; ++n)
#pragma unroll
            for (int r = 0; r < 4; ++r) {
                int row = m0 + t * 16 + quad * 4 + r;
                float v = acc2[t][n][r] + b2v[n];
                if (row < N_NODES) {
                    aggh2[(size_t)row * 128 + n * 16 + r16] = f2bf(v);
                    s[n] += v; q[n] += v * v;
                }
            }
    // reduce over quads (same col set): lanes differ in bits 4,5
#pragma unroll
    for (int n = 0; n < 8; ++n) {
        s[n] += __shfl_xor(s[n], 16); q[n] += __shfl_xor(q[n], 16);
        s[n] += __shfl_xor(s[n], 32); q[n] += __shfl_xor(q[n], 32);
    }
    __syncthreads();          // bn[] zero-init visible
    if (quad == 0) {          // 16 lanes per wave x 4 waves -> LDS atomics
#pragma unroll
        for (int n = 0; n < 8; ++n) {
            atomicAdd(&bn[n * 16 + r16], s[n]);
            atomicAdd(&bn[128 + n * 16 + r16], q[n]);
        }
    }
    __syncthreads();
    atomicAdd(&bnsum[threadIdx.x], bn[threadIdx.x]);   // one device atomic per thread
}

// ---------------- BN finalize + apply (fused; +relu for layer 0 -> bf16 h; layer 1 -> fp32 out) ----------------
__global__ void k_bnnorm(const uint4* __restrict__ h2, const float* __restrict__ bnsum,
                         const float* __restrict__ gamma, const float* __restrict__ beta,
                         uint4* __restrict__ outb, float4* __restrict__ outf, int mode) {
    __shared__ float ab[256];
    int tid = threadIdx.x;
    if (tid < 128) {
        float mean = bnsum[tid] * (1.f / N_NODES);
        float var  = bnsum[128 + tid] * (1.f / N_NODES) - mean * mean;
        float rstd = rsqrtf(var + BN_EPS);
        float g = gamma[tid];
        ab[tid]       = g * rstd;                       // scale
        ab[128 + tid] = beta[tid] - mean * g * rstd;    // shift
    }
    __syncthreads();
    int idx = blockIdx.x * 256 + tid;          // [0, N*16) uint4 units (8 channels each)
    if (idx >= N_NODES * 16) return;
    int p = (idx & 15) * 8;                    // starting channel
    uint4 hv = h2[idx];
    float v0 = bflo(hv.x) * ab[p + 0] + ab[128 + p + 0];
    float v1 = bfhi(hv.x) * ab[p + 1] + ab[128 + p + 1];
    float v2 = bflo(hv.y) * ab[p + 2] + ab[128 + p + 2];
    float v3 = bfhi(hv.y) * ab[p + 3] + ab[128 + p + 3];
    float v4 = bflo(hv.z) * ab[p + 4] + ab[128 + p + 4];
    float v5 = bfhi(hv.z) * ab[p + 5] + ab[128 + p + 5];
    float v6 = bflo(hv.w) * ab[p + 6] + ab[128 + p + 6];
    float v7 = bfhi(hv.w) * ab[p + 7] + ab[128 + p + 7];
    if (mode == 0) {
        v0 = v0 > 0.f ? v0 : 0.f; v1 = v1 > 0.f ? v1 : 0.f;
        v2 = v2 > 0.f ? v2 : 0.f; v3 = v3 > 0.f ? v3 : 0.f;
        v4 = v4 > 0.f ? v4 : 0.f; v5 = v5 > 0.f ? v5 : 0.f;
        v6 = v6 > 0.f ? v6 : 0.f; v7 = v7 > 0.f ? v7 : 0.f;
        uint4 out;
        out.x = packbf(v0, v1); out.y = packbf(v2, v3);
        out.z = packbf(v4, v5); out.w = packbf(v6, v7);
        outb[idx] = out;
    } else {
        outf[2 * idx]     = make_float4(v0, v1, v2, v3);
        outf[2 * idx + 1] = make_float4(v4, v5, v6, v7);
    }
}

extern "C" void kernel_launch(void* const* d_in, const int* in_sizes, int n_in,
                              void* d_out, int out_size, void* d_ws, size_t ws_size,
                              hipStream_t stream) {
    const int* x  = (const int*)d_in[0];
    const int* ei = (const int*)d_in[1];
    const int* ea = (const int*)d_in[2];
    // d_in[3] = batch (unused)
    const float* xe1 = (const float*)d_in[4];
    const float* xe2 = (const float*)d_in[5];
    const float* e1  = (const float*)d_in[6];   // [2][7][128]
    const float* e2  = (const float*)d_in[7];   // [2][3][128]
    const float* W1  = (const float*)d_in[8];   // [2][128][256]
    const float* b1  = (const float*)d_in[9];   // [2][256]
    const float* W2  = (const float*)d_in[10];  // [2][256][128]
    const float* b2  = (const float*)d_in[11];  // [2][128]
    const float* gm  = (const float*)d_in[12];  // [2][128]
    const float* bt  = (const float*)d_in[13];  // [2][128]

    char* ws = (char*)d_ws;
    size_t off = 0;
    auto take = [&](size_t bytes) -> char* {
        char* p = ws + off;
        off = (off + bytes + 255) & ~(size_t)255;
        return p;
    };
    unsigned int* h_buf = (unsigned int*)take((size_t)(N_NODES + 1) * 64 * 4); // +1 zero row
    unsigned int* aggb  = (unsigned int*)take((size_t)NPAD * 64 * 4);          // agg, then h2
    unsigned short* w1t = (unsigned short*)take((size_t)2 * 32768 * 2);
    unsigned short* w2t = (unsigned short*)take((size_t)2 * 32768 * 2);
    int* deg    = (int*)take((size_t)N_NODES * 4);
    int* offs   = (int*)take((size_t)(N_NODES + 1) * 4);
    int* cursor = (int*)take((size_t)N_NODES * 4);
    int* keys   = (int*)take((size_t)(N_EDGES + N_NODES * 16) * 4);
    int* keyv   = (int*)take((size_t)N_EDGES * 4);
    int* bsums  = (int*)take(64 * 4);
    float* bnsum = (float*)take(512 * 4);       // [2][256]
    int* bmeta  = (int*)take(16 * 4);           // bcnt[8], bcur[8]
    int* perm   = (int*)take((size_t)N_NODES * 4);
    int* bcnt = bmeta, *bcur = bmeta + 8;

    k_prep<<<((N_NODES + 1) * 64 + 255) / 256, 256, 0, stream>>>(x, xe1, xe2, h_buf,
                                                                 W1, W2, w1t, w2t, deg,
                                                                 ei, ea, keyv, bnsum, bmeta);
    k_hist<<<8 * NCHUNKS, 256, 0, stream>>>(ei + N_EDGES, deg);
    k_scan1<<<49, 1024, 0, stream>>>(deg, offs, bsums);   // offs used as 'part' scratch here
    k_scan3<<<(N_NODES + 255) / 256, 256, 0, stream>>>(offs, bsums, deg, offs, cursor, keys, bcnt);
    k_fill<<<8 * NCHUNKS, 256, 0, stream>>>(ei + N_EDGES, keyv, cursor, keys,
                                            deg, bcnt, bcur, perm);

    for (int l = 0; l < 2; ++l) {
        k_agg<<<NPAD / 16, 256, 0, stream>>>(h_buf, offs, keys, perm,
                                             e1 + l * 896, e2 + l * 384, aggb);
        k_mlp<<<MBLK, 256, 0, stream>>>((unsigned short*)aggb, w1t + l * 32768, b1 + l * 256,
                                        w2t + l * 32768, b2 + l * 128, bnsum + l * 256);
        k_bnnorm<<<(N_NODES * 16 + 255) / 256, 256, 0, stream>>>((const uint4*)aggb, bnsum + l * 256,
                                                                 gm + l * 128, bt + l * 128,
                                                                 (uint4*)h_buf, (float4*)d_out, l);
    }
}

// Round 4
// 373.707 us; speedup vs baseline: 1.0246x; 1.0246x over previous
//
#include <hip/hip_runtime.h>
#include <stdint.h>

#define N_NODES 50000
#define N_EDGES 800000
#define EMB 128
#define NPAD 50176        // padded to multiple of 128 rows for MLP (392 blocks x 128)
#define MBLK 392          // NPAD / 128
#define BN_EPS 1e-5f
#define SENT_KEY ((N_NODES << 5) | 21)   // sentinel: zero h-row, zero e12 entry
#define NODES_PER_XCD 6250               // 50000 / 8
#define XCHUNK 2048
#define NCHUNKS ((N_EDGES + XCHUNK - 1) / XCHUNK)   // 391
#define PBLK 196                          // ceil(N_NODES/256) blocks doing perm build

typedef __attribute__((ext_vector_type(8))) short short8;
typedef __attribute__((ext_vector_type(4))) float f32x4;

__device__ __forceinline__ unsigned short f2bf(float f) {
    unsigned int u = __float_as_uint(f);
    u += 0x7fffu + ((u >> 16) & 1u);   // RNE; values finite
    return (unsigned short)(u >> 16);
}
__device__ __forceinline__ float bflo(unsigned int v) { return __uint_as_float(v << 16); }
__device__ __forceinline__ float bfhi(unsigned int v) { return __uint_as_float(v & 0xffff0000u); }
__device__ __forceinline__ unsigned int packbf(float lo, float hi) {
    return (unsigned int)f2bf(lo) | ((unsigned int)f2bf(hi) << 16);
}

// ------- fused prep: embedding + zero(deg/bn/buckets) + weight transpose/cast + key precompute -------
__global__ void k_prep(const int* __restrict__ x, const float* __restrict__ xe1,
                       const float* __restrict__ xe2, unsigned int* __restrict__ h,
                       const float* __restrict__ W1, const float* __restrict__ W2,
                       unsigned short* __restrict__ w1t, unsigned short* __restrict__ w2t,
                       int* __restrict__ deg,
                       const int* __restrict__ ei, const int* __restrict__ ea,
                       int* __restrict__ keyv, float* __restrict__ bnsum,
                       int* __restrict__ bmeta) {
    int idx = blockIdx.x * 256 + threadIdx.x;   // [0, (N+1)*64)
    int i = idx >> 6, j = idx & 63;
    if (i < N_NODES) {
        int a = x[2 * i], c = x[2 * i + 1];
        float2 va = *(const float2*)(xe1 + a * EMB + j * 2);
        float2 vb = *(const float2*)(xe2 + c * EMB + j * 2);
        h[i * 64 + j] = packbf(va.x + vb.x, va.y + vb.y);
    } else if (i == N_NODES) {
        h[(size_t)i * 64 + j] = 0u;             // zero sentinel row
    }
    if (idx < 4 * 32768) {                      // weight transpose+cast
        int sec = idx >> 15, q = idx & 32767;
        if (sec < 2) {       // W1[sec]: [128][256] -> w1t[sec][c*128+r]
            int r = q >> 8, c = q & 255;
            w1t[sec * 32768 + c * 128 + r] = f2bf(W1[sec * 32768 + q]);
        } else {             // W2[sec-2]: [256][128] -> w2t[sec-2][c*256+r]
            int s = sec - 2;
            int r = q >> 7, c = q & 127;
            w2t[s * 32768 + c * 256 + r] = f2bf(W2[s * 32768 + q]);
        }
    }
    if (idx < N_EDGES) {                        // packed key precompute
        int2 aa = *(const int2*)(ea + 2 * idx);
        keyv[idx] = (ei[idx] << 5) | (aa.x * 3 + aa.y);
    }
    if (idx < N_NODES) deg[idx] = 0;
    if (idx < 512) bnsum[idx] = 0.f;            // [2][256] BN accumulators
    if (idx < 16) bmeta[idx] = 0;               // bcnt[8] + bcur[8]
}

// ---------------- CSR build (padded-to-16 per node), XCD-partitioned -------------
__global__ void k_hist(const int* __restrict__ dst, int* __restrict__ deg) {
    int xcd = blockIdx.x & 7, chunk = blockIdx.x >> 3;
    int lo = xcd * NODES_PER_XCD, hi = lo + NODES_PER_XCD;
    int e0 = chunk * XCHUNK + threadIdx.x * 4;
#pragma unroll
    for (int it = 0; it < XCHUNK / 1024; ++it) {
        int e = e0 + it * 1024;
        if (e < N_EDGES) {
            int4 d4 = *(const int4*)(dst + e);
            if (d4.x >= lo && d4.x < hi) atomicAdd(&deg[d4.x], 1);
            if (d4.y >= lo && d4.y < hi) atomicAdd(&deg[d4.y], 1);
            if (d4.z >= lo && d4.z < hi) atomicAdd(&deg[d4.z], 1);
            if (d4.w >= lo && d4.w < hi) atomicAdd(&deg[d4.w], 1);
        }
    }
}

// scan over PADDED degrees (pdeg=ceil(deg/16)*16) — shfl-based, 2 barriers
__global__ void k_scan1(const int* __restrict__ deg, int* __restrict__ part, int* __restrict__ bsums) {
    __shared__ int wsum[16];
    int lane = threadIdx.x & 63, wid = threadIdx.x >> 6;
    int i = blockIdx.x * 1024 + threadIdx.x;
    int d = (i < N_NODES) ? deg[i] : 0;
    int v = (d + 15) & ~15;
    int s = v;
#pragma unroll
    for (int off = 1; off < 64; off <<= 1) {
        int t = __shfl_up(s, off);
        if (lane >= off) s += t;
    }
    if (lane == 63) wsum[wid] = s;
    __syncthreads();
    if (wid == 0) {
        int w = (lane < 16) ? wsum[lane] : 0;
#pragma unroll
        for (int off = 1; off < 16; off <<= 1) {
            int t = __shfl_up(w, off);
            if (lane >= off) w += t;
        }
        if (lane < 16) wsum[lane] = w;   // inclusive wave-sum scan
    }
    __syncthreads();
    int base = (wid > 0) ? wsum[wid - 1] : 0;
    if (i < N_NODES) part[i] = base + s - v;   // exclusive within block
    if (threadIdx.x == 1023) bsums[blockIdx.x] = wsum[15];
}

// scan finalize + sentinel padding + per-block bucket counts (for degree sort)
__global__ void k_scan3(const int* __restrict__ part, const int* __restrict__ bsums,
                        const int* __restrict__ deg, int* __restrict__ offs,
                        int* __restrict__ cursor, int* __restrict__ keys,
                        int* __restrict__ bcnt) {
    __shared__ int bs[64];
    __shared__ int lc[8];
    int tid = threadIdx.x;
    if (tid < 8) lc[tid] = 0;
    if (tid < 64) {                       // wave 0 scans the 49 block sums (exclusive)
        int v = (tid < 49) ? bsums[tid] : 0;
        int orig = v;
#pragma unroll
        for (int off = 1; off < 64; off <<= 1) {
            int t = __shfl_up(v, off);
            if (tid >= off) v += t;
        }
        bs[tid] = v - orig;
    }
    __syncthreads();
    int i = blockIdx.x * 256 + tid;
    if (i < N_NODES) {
        int o = part[i] + bs[i >> 10];
        offs[i] = o;
        cursor[i] = o;
        int d = deg[i], pd = (d + 15) & ~15;
        for (int j = d; j < pd; ++j) keys[o + j] = SENT_KEY;
        if (i == N_NODES - 1) offs[N_NODES] = o + pd;
        int nch = pd >> 4;
        atomicAdd(&lc[nch > 7 ? 7 : nch], 1);
    }
    __syncthreads();
    if (tid < 8) atomicAdd(&bcnt[tid], lc[tid]);
}

// fill packed keys via keyv gather (XCD-partitioned) + build degree-bucket permutation
__global__ void k_fill(const int* __restrict__ dst, const int* __restrict__ keyv,
                       int* __restrict__ cursor, int* __restrict__ keys,
                       const int* __restrict__ deg, const int* __restrict__ bcnt,
                       int* __restrict__ bcur, int* __restrict__ perm) {
    int xcd = blockIdx.x & 7, chunk = blockIdx.x >> 3;
    int lo = xcd * NODES_PER_XCD, hi = lo + NODES_PER_XCD;
    int e0 = chunk * XCHUNK + threadIdx.x * 4;
#pragma unroll
    for (int it = 0; it < XCHUNK / 1024; ++it) {
        int e = e0 + it * 1024;
        if (e < N_EDGES) {
            int4 d4 = *(const int4*)(dst + e);
            int dv[4] = {d4.x, d4.y, d4.z, d4.w};
#pragma unroll
            for (int q = 0; q < 4; ++q) {
                int d = dv[q];
                if (d >= lo && d < hi) {
                    int p = atomicAdd(&cursor[d], 1);
                    keys[p] = keyv[e + q];
                }
            }
        }
    }
    // degree-bucket counting sort: first PBLK blocks place their 256 nodes
    if (blockIdx.x < PBLK) {
        __shared__ int lcnt[8], gbase[8], tbase[8];
        if (threadIdx.x < 8) lcnt[threadIdx.x] = 0;
        __syncthreads();
        int i = blockIdx.x * 256 + threadIdx.x;
        int b = 0, lrank = 0;
        if (i < N_NODES) {
            int nch = (deg[i] + 15) >> 4;
            b = nch > 7 ? 7 : nch;
            lrank = atomicAdd(&lcnt[b], 1);
        }
        __syncthreads();
        if (threadIdx.x < 8) {
            gbase[threadIdx.x] = atomicAdd(&bcur[threadIdx.x], lcnt[threadIdx.x]);
            int s = 0;
            for (int k = 0; k < threadIdx.x; ++k) s += bcnt[k];
            tbase[threadIdx.x] = s;
        }
        __syncthreads();
        if (i < N_NODES) perm[tbase[b] + gbase[b] + lrank] = i;
    }
}

// ---------------- aggregation: one node per 16-lane group, degree-sorted slots -------------
// Strided wave->slot map kills sorted-order tail imbalance; two-batch register
// staging keeps ~9-10 gathers in flight per wave (VGPR cap 128 via launch_bounds).
__global__ __launch_bounds__(256, 4) void k_agg(
    const unsigned int* __restrict__ h,        // [(N+1)][64] packed bf16x2 (row N = zeros)
    const int* __restrict__ offs,              // [N+1] padded offsets
    const int* __restrict__ keys,              // padded packed keys
    const int* __restrict__ perm,              // degree-bucket-sorted node ids
    const float* __restrict__ e1l, const float* __restrict__ e2l,
    unsigned int* __restrict__ agg)            // [NPAD][64] packed bf16x2
{
    __shared__ float e12[22 * 132];            // stride 132 staggers rows across banks
    for (int t = threadIdx.x; t < 22 * 128; t += 256) {
        int combo = t >> 7, f = t & 127;
        float v = 0.f;
        if (combo < 21) {
            int a0 = combo / 3, a1 = combo - a0 * 3;
            v = e1l[a0 * EMB + f] + e2l[a1 * EMB + f];
        }
        e12[combo * 132 + f] = v;
    }
    __syncthreads();
    int wave = threadIdx.x >> 6, lane = threadIdx.x & 63;
    int sub = lane >> 4, fl = lane & 15;
    int wi = blockIdx.x * 4 + wave;              // global wave id in [0, 12544)
    int q = (wi & 255) * 49 + (wi >> 8);         // bijection (12544 = 256*49): spread degrees
    int slot = q * 4 + sub;                      // wave keeps 4 CONSECUTIVE sorted slots
    int node = (slot < N_NODES) ? perm[slot] : slot;
    float ax[8] = {0.f, 0.f, 0.f, 0.f, 0.f, 0.f, 0.f, 0.f};
    int o = 0, nch = 0;
    if (node < N_NODES) {
        o = offs[node];
        nch = (offs[node + 1] - o) >> 4;
        // self loop: attr=[4,0] -> combo 12
        uint4 hv = *(const uint4*)(h + (size_t)node * 64 + fl * 4);
        const float* ep = e12 + 12 * 132 + fl * 8;
        float4 e0 = *(const float4*)ep, e1_ = *(const float4*)(ep + 4);
        ax[0] = bflo(hv.x) + e0.x;  ax[1] = bfhi(hv.x) + e0.y;
        ax[2] = bflo(hv.y) + e0.z;  ax[3] = bfhi(hv.y) + e0.w;
        ax[4] = bflo(hv.z) + e1_.x; ax[5] = bfhi(hv.z) + e1_.y;
        ax[6] = bflo(hv.w) + e1_.z; ax[7] = bfhi(hv.w) + e1_.w;
    }
    int maxch = nch;
#pragma unroll
    for (int d = 32; d; d >>= 1) maxch = max(maxch, __shfl_xor(maxch, d));
    int key = (0 < nch) ? keys[o + fl] : SENT_KEY;
    for (int c = 0; c < maxch; ++c) {
        int keyn = (c + 1 < nch) ? keys[o + (c + 1) * 16 + fl] : SENT_KEY;
        int kjA[8], kjB[8];
        uint4 g[8];
        // batch A: issue 8 independent gathers
#pragma unroll
        for (int j = 0; j < 8; ++j) {
            kjA[j] = __shfl(key, sub * 16 + j);
            g[j] = *(const uint4*)(h + (size_t)(kjA[j] >> 5) * 64 + fl * 4);
        }
        // consume A while reissuing slot into batch B
#pragma unroll
        for (int j = 0; j < 8; ++j) {
            uint4 gg = g[j];
            kjB[j] = __shfl(key, sub * 16 + 8 + j);
            g[j] = *(const uint4*)(h + (size_t)(kjB[j] >> 5) * 64 + fl * 4);
            const float* ep = e12 + (kjA[j] & 31) * 132 + fl * 8;
            float4 e0 = *(const float4*)ep, e1_ = *(const float4*)(ep + 4);
            ax[0] += bflo(gg.x) + e0.x;  ax[1] += bfhi(gg.x) + e0.y;
            ax[2] += bflo(gg.y) + e0.z;  ax[3] += bfhi(gg.y) + e0.w;
            ax[4] += bflo(gg.z) + e1_.x; ax[5] += bfhi(gg.z) + e1_.y;
            ax[6] += bflo(gg.w) + e1_.z; ax[7] += bfhi(gg.w) + e1_.w;
        }
        // drain batch B
#pragma unroll
        for (int j = 0; j < 8; ++j) {
            uint4 gg = g[j];
            const float* ep = e12 + (kjB[j] & 31) * 132 + fl * 8;
            float4 e0 = *(const float4*)ep, e1_ = *(const float4*)(ep + 4);
            ax[0] += bflo(gg.x) + e0.x;  ax[1] += bfhi(gg.x) + e0.y;
            ax[2] += bflo(gg.y) + e0.z;  ax[3] += bfhi(gg.y) + e0.w;
            ax[4] += bflo(gg.z) + e1_.x; ax[5] += bfhi(gg.z) + e1_.y;
            ax[6] += bflo(gg.w) + e1_.z; ax[7] += bfhi(gg.w) + e1_.w;
        }
        key = keyn;
    }
    {
        uint4 out;
        out.x = packbf(ax[0], ax[1]); out.y = packbf(ax[2], ax[3]);
        out.z = packbf(ax[4], ax[5]); out.w = packbf(ax[6], ax[7]);
        *(uint4*)(agg + (size_t)node * 64 + fl * 4) = out;   // pad rows -> zeros
    }
}

// ---------------- fused MLP + BN stats: h2 = relu(agg@W1+b1)@W2+b2 ----------------
__global__ __launch_bounds__(256, 2) void k_mlp(
    unsigned short* aggh2,                     // [NPAD][128] bf16 in, [N][128] bf16 out
    const unsigned short* __restrict__ w1t,    // [256][128]  (W1 transposed: [n][k])
    const float* __restrict__ b1,              // [256]
    const unsigned short* __restrict__ w2t,    // [128][256]  (W2 transposed: [n][k])
    const float* __restrict__ b2,              // [128]
    float* __restrict__ bnsum)                 // [256]: cols 0..127 sum, 128..255 sumsq
{
    __shared__ float bn[256];
    int lane = threadIdx.x & 63;
    int wave = threadIdx.x >> 6;
    int quad = lane >> 4, r16 = lane & 15;
    int m0 = (blockIdx.x * 4 + wave) * 32;     // 32 rows per wave
    int sel  = (lane >> 5) & 1;
    int srcA = ((lane >> 4) & 1) * 32 + r16;
    int srcB = srcA + 16;
    bn[threadIdx.x] = 0.f;

    // agg B-frags (GEMM1 swapped): B[k=quad*8+j][node=r16]
    short8 bagg[2][4];
#pragma unroll
    for (int t = 0; t < 2; ++t)
#pragma unroll
        for (int c = 0; c < 4; ++c)
            bagg[t][c] = *(const short8*)(aggh2 + (size_t)(m0 + t * 16 + r16) * 128 + c * 32 + quad * 8);

    float b2v[8];
#pragma unroll
    for (int n = 0; n < 8; ++n) b2v[n] = b2[n * 16 + r16];

    f32x4 acc2[2][8];
#pragma unroll
    for (int t = 0; t < 2; ++t)
#pragma unroll
        for (int n = 0; n < 8; ++n) acc2[t][n] = (f32x4){0.f, 0.f, 0.f, 0.f};

    for (int c2 = 0; c2 < 8; ++c2) {
        unsigned int pk[2][2][2];              // [ntl][tile][dword]
#pragma unroll
        for (int ntl = 0; ntl < 2; ++ntl) {
            int nt = c2 * 2 + ntl;
            short8 aw[4];
#pragma unroll
            for (int c = 0; c < 4; ++c)
                aw[c] = *(const short8*)(w1t + (nt * 16 + r16) * 128 + c * 32 + quad * 8);
            float4 bv = *(const float4*)(b1 + nt * 16 + quad * 4);
#pragma unroll
            for (int t = 0; t < 2; ++t) {
                f32x4 a1 = {0.f, 0.f, 0.f, 0.f};
#pragma unroll
                for (int c = 0; c < 4; ++c)
                    a1 = __builtin_amdgcn_mfma_f32_16x16x32_bf16(aw[c], bagg[t][c], a1, 0, 0, 0);
                float v0 = a1[0] + bv.x; v0 = v0 > 0.f ? v0 : 0.f;
                float v1 = a1[1] + bv.y; v1 = v1 > 0.f ? v1 : 0.f;
                float v2 = a1[2] + bv.z; v2 = v2 > 0.f ? v2 : 0.f;
                float v3 = a1[3] + bv.w; v3 = v3 > 0.f ? v3 : 0.f;
                pk[ntl][t][0] = packbf(v0, v1);
                pk[ntl][t][1] = packbf(v2, v3);
            }
        }
        short8 a2f[2];
#pragma unroll
        for (int t = 0; t < 2; ++t) {
            int u0 = __shfl((int)pk[0][t][0], srcA), w0 = __shfl((int)pk[1][t][0], srcA);
            int u1 = __shfl((int)pk[0][t][1], srcA), w1_ = __shfl((int)pk[1][t][1], srcA);
            int u2 = __shfl((int)pk[0][t][0], srcB), w2_ = __shfl((int)pk[1][t][0], srcB);
            int u3 = __shfl((int)pk[0][t][1], srcB), w3_ = __shfl((int)pk[1][t][1], srcB);
            union { int i[4]; short8 s; } a2u;
            a2u.i[0] = sel ? w0 : u0;
            a2u.i[1] = sel ? w1_ : u1;
            a2u.i[2] = sel ? w2_ : u2;
            a2u.i[3] = sel ? w3_ : u3;
            a2f[t] = a2u.s;
        }
#pragma unroll
        for (int n = 0; n < 8; ++n) {
            short8 bw = *(const short8*)(w2t + (n * 16 + r16) * 256 + c2 * 32 + quad * 8);
            acc2[0][n] = __builtin_amdgcn_mfma_f32_16x16x32_bf16(a2f[0], bw, acc2[0][n], 0, 0, 0);
            acc2[1][n] = __builtin_amdgcn_mfma_f32_16x16x32_bf16(a2f[1], bw, acc2[1][n], 0, 0, 0);
        }
    }
    // epilogue: store h2 + accumulate per-lane BN partial sums (fp32, rows < N only)
    float s[8], q[8];
#pragma unroll
    for (int n = 0; n < 8; ++n) { s[n] = 0.f; q[n] = 0.f; }
#pragma unroll
    for (int t = 0; t < 2; ++t)
#pragma unroll
        for (int n = 0; n < 8; ++n)
#pragma unroll
            for (int r = 0; r < 4; ++r) {
                int row = m0 + t * 16 + quad * 4 + r;
                float v = acc2[t][n][r] + b2v[n];
                if (row < N_NODES) {
                    aggh2[(size_t)row * 128 + n * 16 + r16] = f2bf(v);
                    s[n] += v; q[n] += v * v;
                }
            }
    // reduce over quads (same col set): lanes differ in bits 4,5
#pragma unroll
    for (int n = 0; n < 8; ++n) {
        s[n] += __shfl_xor(s[n], 16); q[n] += __shfl_xor(q[n], 16);
        s[n] += __shfl_xor(s[n], 32); q[n] += __shfl_xor(q[n], 32);
    }
    __syncthreads();          // bn[] zero-init visible
    if (quad == 0) {          // 16 lanes per wave x 4 waves -> LDS atomics
#pragma unroll
        for (int n = 0; n < 8; ++n) {
            atomicAdd(&bn[n * 16 + r16], s[n]);
            atomicAdd(&bn[128 + n * 16 + r16], q[n]);
        }
    }
    __syncthreads();
    atomicAdd(&bnsum[threadIdx.x], bn[threadIdx.x]);   // one device atomic per thread
}

// ---------------- BN finalize + apply (fused; +relu for layer 0 -> bf16 h; layer 1 -> fp32 out) ----------------
__global__ void k_bnnorm(const uint4* __restrict__ h2, const float* __restrict__ bnsum,
                         const float* __restrict__ gamma, const float* __restrict__ beta,
                         uint4* __restrict__ outb, float4* __restrict__ outf, int mode) {
    __shared__ float ab[256];
    int tid = threadIdx.x;
    if (tid < 128) {
        float mean = bnsum[tid] * (1.f / N_NODES);
        float var  = bnsum[128 + tid] * (1.f / N_NODES) - mean * mean;
        float rstd = rsqrtf(var + BN_EPS);
        float g = gamma[tid];
        ab[tid]       = g * rstd;                       // scale
        ab[128 + tid] = beta[tid] - mean * g * rstd;    // shift
    }
    __syncthreads();
    int idx = blockIdx.x * 256 + tid;          // [0, N*16) uint4 units (8 channels each)
    if (idx >= N_NODES * 16) return;
    int p = (idx & 15) * 8;                    // starting channel
    uint4 hv = h2[idx];
    float v0 = bflo(hv.x) * ab[p + 0] + ab[128 + p + 0];
    float v1 = bfhi(hv.x) * ab[p + 1] + ab[128 + p + 1];
    float v2 = bflo(hv.y) * ab[p + 2] + ab[128 + p + 2];
    float v3 = bfhi(hv.y) * ab[p + 3] + ab[128 + p + 3];
    float v4 = bflo(hv.z) * ab[p + 4] + ab[128 + p + 4];
    float v5 = bfhi(hv.z) * ab[p + 5] + ab[128 + p + 5];
    float v6 = bflo(hv.w) * ab[p + 6] + ab[128 + p + 6];
    float v7 = bfhi(hv.w) * ab[p + 7] + ab[128 + p + 7];
    if (mode == 0) {
        v0 = v0 > 0.f ? v0 : 0.f; v1 = v1 > 0.f ? v1 : 0.f;
        v2 = v2 > 0.f ? v2 : 0.f; v3 = v3 > 0.f ? v3 : 0.f;
        v4 = v4 > 0.f ? v4 : 0.f; v5 = v5 > 0.f ? v5 : 0.f;
        v6 = v6 > 0.f ? v6 : 0.f; v7 = v7 > 0.f ? v7 : 0.f;
        uint4 out;
        out.x = packbf(v0, v1); out.y = packbf(v2, v3);
        out.z = packbf(v4, v5); out.w = packbf(v6, v7);
        outb[idx] = out;
    } else {
        outf[2 * idx]     = make_float4(v0, v1, v2, v3);
        outf[2 * idx + 1] = make_float4(v4, v5, v6, v7);
    }
}

extern "C" void kernel_launch(void* const* d_in, const int* in_sizes, int n_in,
                              void* d_out, int out_size, void* d_ws, size_t ws_size,
                              hipStream_t stream) {
    const int* x  = (const int*)d_in[0];
    const int* ei = (const int*)d_in[1];
    const int* ea = (const int*)d_in[2];
    // d_in[3] = batch (unused)
    const float* xe1 = (const float*)d_in[4];
    const float* xe2 = (const float*)d_in[5];
    const float* e1  = (const float*)d_in[6];   // [2][7][128]
    const float* e2  = (const float*)d_in[7];   // [2][3][128]
    const float* W1  = (const float*)d_in[8];   // [2][128][256]
    const float* b1  = (const float*)d_in[9];   // [2][256]
    const float* W2  = (const float*)d_in[10];  // [2][256][128]
    const float* b2  = (const float*)d_in[11];  // [2][128]
    const float* gm  = (const float*)d_in[12];  // [2][128]
    const float* bt  = (const float*)d_in[13];  // [2][128]

    char* ws = (char*)d_ws;
    size_t off = 0;
    auto take = [&](size_t bytes) -> char* {
        char* p = ws + off;
        off = (off + bytes + 255) & ~(size_t)255;
        return p;
    };
    unsigned int* h_buf = (unsigned int*)take((size_t)(N_NODES + 1) * 64 * 4); // +1 zero row
    unsigned int* aggb  = (unsigned int*)take((size_t)NPAD * 64 * 4);          // agg, then h2
    unsigned short* w1t = (unsigned short*)take((size_t)2 * 32768 * 2);
    unsigned short* w2t = (unsigned short*)take((size_t)2 * 32768 * 2);
    int* deg    = (int*)take((size_t)N_NODES * 4);
    int* offs   = (int*)take((size_t)(N_NODES + 1) * 4);
    int* cursor = (int*)take((size_t)N_NODES * 4);
    int* keys   = (int*)take((size_t)(N_EDGES + N_NODES * 16) * 4);
    int* keyv   = (int*)take((size_t)N_EDGES * 4);
    int* bsums  = (int*)take(64 * 4);
    float* bnsum = (float*)take(512 * 4);       // [2][256]
    int* bmeta  = (int*)take(16 * 4);           // bcnt[8], bcur[8]
    int* perm   = (int*)take((size_t)N_NODES * 4);
    int* bcnt = bmeta, *bcur = bmeta + 8;

    k_prep<<<((N_NODES + 1) * 64 + 255) / 256, 256, 0, stream>>>(x, xe1, xe2, h_buf,
                                                                 W1, W2, w1t, w2t, deg,
                                                                 ei, ea, keyv, bnsum, bmeta);
    k_hist<<<8 * NCHUNKS, 256, 0, stream>>>(ei + N_EDGES, deg);
    k_scan1<<<49, 1024, 0, stream>>>(deg, offs, bsums);   // offs used as 'part' scratch here
    k_scan3<<<(N_NODES + 255) / 256, 256, 0, stream>>>(offs, bsums, deg, offs, cursor, keys, bcnt);
    k_fill<<<8 * NCHUNKS, 256, 0, stream>>>(ei + N_EDGES, keyv, cursor, keys,
                                            deg, bcnt, bcur, perm);

    for (int l = 0; l < 2; ++l) {
        k_agg<<<NPAD / 16, 256, 0, stream>>>(h_buf, offs, keys, perm,
                                             e1 + l * 896, e2 + l * 384, aggb);
        k_mlp<<<MBLK, 256, 0, stream>>>((unsigned short*)aggb, w1t + l * 32768, b1 + l * 256,
                                        w2t + l * 32768, b2 + l * 128, bnsum + l * 256);
        k_bnnorm<<<(N_NODES * 16 + 255) / 256, 256, 0, stream>>>((const uint4*)aggb, bnsum + l * 256,
                                                                 gm + l * 128, bt + l * 128,
                                                                 (uint4*)h_buf, (float4*)d_out, l);
    }
}

// Round 5
// 365.599 us; speedup vs baseline: 1.0473x; 1.0222x over previous
//
#include <hip/hip_runtime.h>
#include <stdint.h>

#define N_NODES 50000
#define N_EDGES 800000
#define EMB 128
#define NPAD 50176        // padded to multiple of 128 rows for MLP (392 blocks x 128)
#define MBLK 392          // NPAD / 128
#define BN_EPS 1e-5f
#define SENT_KEY ((N_NODES << 5) | 21)   // sentinel: zero h-row, zero e12 entry
#define NODES_PER_XCD 6250               // 50000 / 8
#define XCHUNK 2048
#define NCHUNKS ((N_EDGES + XCHUNK - 1) / XCHUNK)   // 391
#define PBLK 196                          // ceil(N_NODES/256)

typedef __attribute__((ext_vector_type(8))) short short8;
typedef __attribute__((ext_vector_type(4))) float f32x4;

__device__ __forceinline__ unsigned short f2bf(float f) {
    unsigned int u = __float_as_uint(f);
    u += 0x7fffu + ((u >> 16) & 1u);   // RNE; values finite
    return (unsigned short)(u >> 16);
}
__device__ __forceinline__ float bflo(unsigned int v) { return __uint_as_float(v << 16); }
__device__ __forceinline__ float bfhi(unsigned int v) { return __uint_as_float(v & 0xffff0000u); }
__device__ __forceinline__ unsigned int packbf(float lo, float hi) {
    return (unsigned int)f2bf(lo) | ((unsigned int)f2bf(hi) << 16);
}

// ------- fused prep: embedding + weight transpose/cast + key precompute + dst histogram -------
// deg/bnsum/bmeta are pre-zeroed by one hipMemsetAsync before this kernel.
__global__ void k_prep(const int* __restrict__ x, const float* __restrict__ xe1,
                       const float* __restrict__ xe2, unsigned int* __restrict__ h,
                       const float* __restrict__ W1, const float* __restrict__ W2,
                       unsigned short* __restrict__ w1t, unsigned short* __restrict__ w2t,
                       int* __restrict__ deg,
                       const int* __restrict__ ei, const int* __restrict__ ea,
                       int* __restrict__ keyv) {
    int idx = blockIdx.x * 256 + threadIdx.x;   // [0, (N+1)*64)
    int i = idx >> 6, j = idx & 63;
    if (i < N_NODES) {
        int a = x[2 * i], c = x[2 * i + 1];
        float2 va = *(const float2*)(xe1 + a * EMB + j * 2);
        float2 vb = *(const float2*)(xe2 + c * EMB + j * 2);
        h[i * 64 + j] = packbf(va.x + vb.x, va.y + vb.y);
    } else if (i == N_NODES) {
        h[(size_t)i * 64 + j] = 0u;             // zero sentinel row
    }
    if (idx < 4 * 32768) {                      // weight transpose+cast
        int sec = idx >> 15, q = idx & 32767;
        if (sec < 2) {       // W1[sec]: [128][256] -> w1t[sec][c*128+r]
            int r = q >> 8, c = q & 255;
            w1t[sec * 32768 + c * 128 + r] = f2bf(W1[sec * 32768 + q]);
        } else {             // W2[sec-2]: [256][128] -> w2t[sec-2][c*256+r]
            int s = sec - 2;
            int r = q >> 7, c = q & 127;
            w2t[s * 32768 + c * 256 + r] = f2bf(W2[s * 32768 + q]);
        }
    }
    if (idx < N_EDGES) {                        // packed key precompute + histogram
        int2 aa = *(const int2*)(ea + 2 * idx);
        keyv[idx] = (ei[idx] << 5) | (aa.x * 3 + aa.y);
        atomicAdd(&deg[ei[N_EDGES + idx]], 1);  // dst degree
    }
}

// ---------------- CSR region allocation (unordered): one atomic per block ----------------
// Replaces the 2-phase prefix scan: offsets need not be ordered, only disjoint.
// Also fuses sentinel padding and per-bucket node counts (for the degree sort).
__global__ void k_alloc(const int* __restrict__ deg, int* __restrict__ gcur,
                        int* __restrict__ offs, int* __restrict__ cursor,
                        int* __restrict__ keys, int* __restrict__ bcnt) {
    __shared__ int wbase[4];
    __shared__ int lc[8];
    int tid = threadIdx.x, lane = tid & 63, wid = tid >> 6;
    if (tid < 8) lc[tid] = 0;
    int i = blockIdx.x * 256 + tid;
    int d = (i < N_NODES) ? deg[i] : 0;
    int pd = (d + 15) & ~15;
    int s = pd;                                  // wave inclusive scan
#pragma unroll
    for (int off = 1; off < 64; off <<= 1) {
        int t = __shfl_up(s, off);
        if (lane >= off) s += t;
    }
    if (lane == 63) wbase[wid] = s;
    __syncthreads();
    if (tid == 0) {                              // one global atomic per block
        int t0 = wbase[0], t1 = wbase[1], t2 = wbase[2], t3 = wbase[3];
        int b = atomicAdd(gcur, t0 + t1 + t2 + t3);
        wbase[0] = b; wbase[1] = b + t0; wbase[2] = b + t0 + t1; wbase[3] = b + t0 + t1 + t2;
    }
    __syncthreads();
    if (i < N_NODES) {
        int o = wbase[wid] + s - pd;             // exclusive within wave
        offs[i] = o;
        cursor[i] = o;
        for (int j = d; j < pd; ++j) keys[o + j] = SENT_KEY;
        int nch = pd >> 4;
        atomicAdd(&lc[nch > 7 ? 7 : nch], 1);
    }
    __syncthreads();
    if (tid < 8) atomicAdd(&bcnt[tid], lc[tid]);
}

// fill packed keys via keyv gather (XCD-partitioned) + build degree-bucket permutation
__global__ void k_fill(const int* __restrict__ dst, const int* __restrict__ keyv,
                       int* __restrict__ cursor, int* __restrict__ keys,
                       const int* __restrict__ deg, const int* __restrict__ bcnt,
                       int* __restrict__ bcur, int* __restrict__ perm) {
    int xcd = blockIdx.x & 7, chunk = blockIdx.x >> 3;
    int lo = xcd * NODES_PER_XCD, hi = lo + NODES_PER_XCD;
    int e0 = chunk * XCHUNK + threadIdx.x * 4;
#pragma unroll
    for (int it = 0; it < XCHUNK / 1024; ++it) {
        int e = e0 + it * 1024;
        if (e < N_EDGES) {
            int4 d4 = *(const int4*)(dst + e);
            int dv[4] = {d4.x, d4.y, d4.z, d4.w};
#pragma unroll
            for (int q = 0; q < 4; ++q) {
                int d = dv[q];
                if (d >= lo && d < hi) {
                    int p = atomicAdd(&cursor[d], 1);
                    keys[p] = keyv[e + q];
                }
            }
        }
    }
    // degree-bucket counting sort: first PBLK blocks place their 256 nodes
    if (blockIdx.x < PBLK) {
        __shared__ int lcnt[8], gbase[8], tbase[8];
        if (threadIdx.x < 8) lcnt[threadIdx.x] = 0;
        __syncthreads();
        int i = blockIdx.x * 256 + threadIdx.x;
        int b = 0, lrank = 0;
        if (i < N_NODES) {
            int nch = (deg[i] + 15) >> 4;
            b = nch > 7 ? 7 : nch;
            lrank = atomicAdd(&lcnt[b], 1);
        }
        __syncthreads();
        if (threadIdx.x < 8) {
            gbase[threadIdx.x] = atomicAdd(&bcur[threadIdx.x], lcnt[threadIdx.x]);
            int s = 0;
            for (int k = 0; k < threadIdx.x; ++k) s += bcnt[k];
            tbase[threadIdx.x] = s;
        }
        __syncthreads();
        if (i < N_NODES) perm[tbase[b] + gbase[b] + lrank] = i;
    }
}

// ---------------- aggregation: one node per 16-lane group, degree-sorted slots -------------
// Strided wave->slot map kills sorted-order tail imbalance; two-batch register
// staging keeps ~9-10 gathers in flight per wave (VGPR cap 128 via launch_bounds).
// Chunk count comes from deg (offsets are unordered now).
__global__ __launch_bounds__(256, 4) void k_agg(
    const unsigned int* __restrict__ h,        // [(N+1)][64] packed bf16x2 (row N = zeros)
    const int* __restrict__ offs,              // [N] padded region starts (unordered)
    const int* __restrict__ deg,               // [N] real degrees
    const int* __restrict__ keys,              // padded packed keys
    const int* __restrict__ perm,              // degree-bucket-sorted node ids
    const float* __restrict__ e1l, const float* __restrict__ e2l,
    unsigned int* __restrict__ agg)            // [NPAD][64] packed bf16x2
{
    __shared__ float e12[22 * 132];            // stride 132 staggers rows across banks
    for (int t = threadIdx.x; t < 22 * 128; t += 256) {
        int combo = t >> 7, f = t & 127;
        float v = 0.f;
        if (combo < 21) {
            int a0 = combo / 3, a1 = combo - a0 * 3;
            v = e1l[a0 * EMB + f] + e2l[a1 * EMB + f];
        }
        e12[combo * 132 + f] = v;
    }
    __syncthreads();
    int wave = threadIdx.x >> 6, lane = threadIdx.x & 63;
    int sub = lane >> 4, fl = lane & 15;
    int wi = blockIdx.x * 4 + wave;              // global wave id in [0, 12544)
    int q = (wi & 255) * 49 + (wi >> 8);         // bijection (12544 = 256*49): spread degrees
    int slot = q * 4 + sub;                      // wave keeps 4 CONSECUTIVE sorted slots
    int node = (slot < N_NODES) ? perm[slot] : slot;
    float ax[8] = {0.f, 0.f, 0.f, 0.f, 0.f, 0.f, 0.f, 0.f};
    int o = 0, nch = 0;
    if (node < N_NODES) {
        o = offs[node];
        nch = (deg[node] + 15) >> 4;
        // self loop: attr=[4,0] -> combo 12
        uint4 hv = *(const uint4*)(h + (size_t)node * 64 + fl * 4);
        const float* ep = e12 + 12 * 132 + fl * 8;
        float4 e0 = *(const float4*)ep, e1_ = *(const float4*)(ep + 4);
        ax[0] = bflo(hv.x) + e0.x;  ax[1] = bfhi(hv.x) + e0.y;
        ax[2] = bflo(hv.y) + e0.z;  ax[3] = bfhi(hv.y) + e0.w;
        ax[4] = bflo(hv.z) + e1_.x; ax[5] = bfhi(hv.z) + e1_.y;
        ax[6] = bflo(hv.w) + e1_.z; ax[7] = bfhi(hv.w) + e1_.w;
    }
    int maxch = nch;
#pragma unroll
    for (int d = 32; d; d >>= 1) maxch = max(maxch, __shfl_xor(maxch, d));
    int key = (0 < nch) ? keys[o + fl] : SENT_KEY;
    for (int c = 0; c < maxch; ++c) {
        int keyn = (c + 1 < nch) ? keys[o + (c + 1) * 16 + fl] : SENT_KEY;
        int kjA[8], kjB[8];
        uint4 g[8];
        // batch A: issue 8 independent gathers
#pragma unroll
        for (int j = 0; j < 8; ++j) {
            kjA[j] = __shfl(key, sub * 16 + j);
            g[j] = *(const uint4*)(h + (size_t)(kjA[j] >> 5) * 64 + fl * 4);
        }
        // consume A while reissuing slot into batch B
#pragma unroll
        for (int j = 0; j < 8; ++j) {
            uint4 gg = g[j];
            kjB[j] = __shfl(key, sub * 16 + 8 + j);
            g[j] = *(const uint4*)(h + (size_t)(kjB[j] >> 5) * 64 + fl * 4);
            const float* ep = e12 + (kjA[j] & 31) * 132 + fl * 8;
            float4 e0 = *(const float4*)ep, e1_ = *(const float4*)(ep + 4);
            ax[0] += bflo(gg.x) + e0.x;  ax[1] += bfhi(gg.x) + e0.y;
            ax[2] += bflo(gg.y) + e0.z;  ax[3] += bfhi(gg.y) + e0.w;
            ax[4] += bflo(gg.z) + e1_.x; ax[5] += bfhi(gg.z) + e1_.y;
            ax[6] += bflo(gg.w) + e1_.z; ax[7] += bfhi(gg.w) + e1_.w;
        }
        // drain batch B
#pragma unroll
        for (int j = 0; j < 8; ++j) {
            uint4 gg = g[j];
            const float* ep = e12 + (kjB[j] & 31) * 132 + fl * 8;
            float4 e0 = *(const float4*)ep, e1_ = *(const float4*)(ep + 4);
            ax[0] += bflo(gg.x) + e0.x;  ax[1] += bfhi(gg.x) + e0.y;
            ax[2] += bflo(gg.y) + e0.z;  ax[3] += bfhi(gg.y) + e0.w;
            ax[4] += bflo(gg.z) + e1_.x; ax[5] += bfhi(gg.z) + e1_.y;
            ax[6] += bflo(gg.w) + e1_.z; ax[7] += bfhi(gg.w) + e1_.w;
        }
        key = keyn;
    }
    {
        uint4 out;
        out.x = packbf(ax[0], ax[1]); out.y = packbf(ax[2], ax[3]);
        out.z = packbf(ax[4], ax[5]); out.w = packbf(ax[6], ax[7]);
        *(uint4*)(agg + (size_t)node * 64 + fl * 4) = out;   // pad rows -> zeros
    }
}

// ---------------- fused MLP + BN stats: h2 = relu(agg@W1+b1)@W2+b2 ----------------
__global__ __launch_bounds__(256, 2) void k_mlp(
    unsigned short* aggh2,                     // [NPAD][128] bf16 in, [N][128] bf16 out
    const unsigned short* __restrict__ w1t,    // [256][128]  (W1 transposed: [n][k])
    const float* __restrict__ b1,              // [256]
    const unsigned short* __restrict__ w2t,    // [128][256]  (W2 transposed: [n][k])
    const float* __restrict__ b2,              // [128]
    float* __restrict__ bnsum)                 // [256]: cols 0..127 sum, 128..255 sumsq
{
    __shared__ float bn[256];
    int lane = threadIdx.x & 63;
    int wave = threadIdx.x >> 6;
    int quad = lane >> 4, r16 = lane & 15;
    int m0 = (blockIdx.x * 4 + wave) * 32;     // 32 rows per wave
    int sel  = (lane >> 5) & 1;
    int srcA = ((lane >> 4) & 1) * 32 + r16;
    int srcB = srcA + 16;
    bn[threadIdx.x] = 0.f;

    // agg B-frags (GEMM1 swapped): B[k=quad*8+j][node=r16]
    short8 bagg[2][4];
#pragma unroll
    for (int t = 0; t < 2; ++t)
#pragma unroll
        for (int c = 0; c < 4; ++c)
            bagg[t][c] = *(const short8*)(aggh2 + (size_t)(m0 + t * 16 + r16) * 128 + c * 32 + quad * 8);

    float b2v[8];
#pragma unroll
    for (int n = 0; n < 8; ++n) b2v[n] = b2[n * 16 + r16];

    f32x4 acc2[2][8];
#pragma unroll
    for (int t = 0; t < 2; ++t)
#pragma unroll
        for (int n = 0; n < 8; ++n) acc2[t][n] = (f32x4){0.f, 0.f, 0.f, 0.f};

    for (int c2 = 0; c2 < 8; ++c2) {
        unsigned int pk[2][2][2];              // [ntl][tile][dword]
#pragma unroll
        for (int ntl = 0; ntl < 2; ++ntl) {
            int nt = c2 * 2 + ntl;
            short8 aw[4];
#pragma unroll
            for (int c = 0; c < 4; ++c)
                aw[c] = *(const short8*)(w1t + (nt * 16 + r16) * 128 + c * 32 + quad * 8);
            float4 bv = *(const float4*)(b1 + nt * 16 + quad * 4);
#pragma unroll
            for (int t = 0; t < 2; ++t) {
                f32x4 a1 = {0.f, 0.f, 0.f, 0.f};
#pragma unroll
                for (int c = 0; c < 4; ++c)
                    a1 = __builtin_amdgcn_mfma_f32_16x16x32_bf16(aw[c], bagg[t][c], a1, 0, 0, 0);
                float v0 = a1[0] + bv.x; v0 = v0 > 0.f ? v0 : 0.f;
                float v1 = a1[1] + bv.y; v1 = v1 > 0.f ? v1 : 0.f;
                float v2 = a1[2] + bv.z; v2 = v2 > 0.f ? v2 : 0.f;
                float v3 = a1[3] + bv.w; v3 = v3 > 0.f ? v3 : 0.f;
                pk[ntl][t][0] = packbf(v0, v1);
                pk[ntl][t][1] = packbf(v2, v3);
            }
        }
        short8 a2f[2];
#pragma unroll
        for (int t = 0; t < 2; ++t) {
            int u0 = __shfl((int)pk[0][t][0], srcA), w0 = __shfl((int)pk[1][t][0], srcA);
            int u1 = __shfl((int)pk[0][t][1], srcA), w1_ = __shfl((int)pk[1][t][1], srcA);
            int u2 = __shfl((int)pk[0][t][0], srcB), w2_ = __shfl((int)pk[1][t][0], srcB);
            int u3 = __shfl((int)pk[0][t][1], srcB), w3_ = __shfl((int)pk[1][t][1], srcB);
            union { int i[4]; short8 s; } a2u;
            a2u.i[0] = sel ? w0 : u0;
            a2u.i[1] = sel ? w1_ : u1;
            a2u.i[2] = sel ? w2_ : u2;
            a2u.i[3] = sel ? w3_ : u3;
            a2f[t] = a2u.s;
        }
#pragma unroll
        for (int n = 0; n < 8; ++n) {
            short8 bw = *(const short8*)(w2t + (n * 16 + r16) * 256 + c2 * 32 + quad * 8);
            acc2[0][n] = __builtin_amdgcn_mfma_f32_16x16x32_bf16(a2f[0], bw, acc2[0][n], 0, 0, 0);
            acc2[1][n] = __builtin_amdgcn_mfma_f32_16x16x32_bf16(a2f[1], bw, acc2[1][n], 0, 0, 0);
        }
    }
    // epilogue: store h2 + accumulate per-lane BN partial sums (fp32, rows < N only)
    float s[8], q[8];
#pragma unroll
    for (int n = 0; n < 8; ++n) { s[n] = 0.f; q[n] = 0.f; }
#pragma unroll
    for (int t = 0; t < 2; ++t)
#pragma unroll
        for (int n = 0; n < 8; ++n)
#pragma unroll
            for (int r = 0; r < 4; ++r) {
                int row = m0 + t * 16 + quad * 4 + r;
                float v = acc2[t][n][r] + b2v[n];
                if (row < N_NODES) {
                    aggh2[(size_t)row * 128 + n * 16 + r16] = f2bf(v);
                    s[n] += v; q[n] += v * v;
                }
            }
    // reduce over quads (same col set): lanes differ in bits 4,5
#pragma unroll
    for (int n = 0; n < 8; ++n) {
        s[n] += __shfl_xor(s[n], 16); q[n] += __shfl_xor(q[n], 16);
        s[n] += __shfl_xor(s[n], 32); q[n] += __shfl_xor(q[n], 32);
    }
    __syncthreads();          // bn[] zero-init visible
    if (quad == 0) {          // 16 lanes per wave x 4 waves -> LDS atomics
#pragma unroll
        for (int n = 0; n < 8; ++n) {
            atomicAdd(&bn[n * 16 + r16], s[n]);
            atomicAdd(&bn[128 + n * 16 + r16], q[n]);
        }
    }
    __syncthreads();
    atomicAdd(&bnsum[threadIdx.x], bn[threadIdx.x]);   // one device atomic per thread
}

// ---------------- BN finalize + apply (fused; +relu for layer 0 -> bf16 h; layer 1 -> fp32 out) ----------------
__global__ void k_bnnorm(const uint4* __restrict__ h2, const float* __restrict__ bnsum,
                         const float* __restrict__ gamma, const float* __restrict__ beta,
                         uint4* __restrict__ outb, float4* __restrict__ outf, int mode) {
    __shared__ float ab[256];
    int tid = threadIdx.x;
    if (tid < 128) {
        float mean = bnsum[tid] * (1.f / N_NODES);
        float var  = bnsum[128 + tid] * (1.f / N_NODES) - mean * mean;
        float rstd = rsqrtf(var + BN_EPS);
        float g = gamma[tid];
        ab[tid]       = g * rstd;                       // scale
        ab[128 + tid] = beta[tid] - mean * g * rstd;    // shift
    }
    __syncthreads();
    int idx = blockIdx.x * 256 + tid;          // [0, N*16) uint4 units (8 channels each)
    if (idx >= N_NODES * 16) return;
    int p = (idx & 15) * 8;                    // starting channel
    uint4 hv = h2[idx];
    float v0 = bflo(hv.x) * ab[p + 0] + ab[128 + p + 0];
    float v1 = bfhi(hv.x) * ab[p + 1] + ab[128 + p + 1];
    float v2 = bflo(hv.y) * ab[p + 2] + ab[128 + p + 2];
    float v3 = bfhi(hv.y) * ab[p + 3] + ab[128 + p + 3];
    float v4 = bflo(hv.z) * ab[p + 4] + ab[128 + p + 4];
    float v5 = bfhi(hv.z) * ab[p + 5] + ab[128 + p + 5];
    float v6 = bflo(hv.w) * ab[p + 6] + ab[128 + p + 6];
    float v7 = bfhi(hv.w) * ab[p + 7] + ab[128 + p + 7];
    if (mode == 0) {
        v0 = v0 > 0.f ? v0 : 0.f; v1 = v1 > 0.f ? v1 : 0.f;
        v2 = v2 > 0.f ? v2 : 0.f; v3 = v3 > 0.f ? v3 : 0.f;
        v4 = v4 > 0.f ? v4 : 0.f; v5 = v5 > 0.f ? v5 : 0.f;
        v6 = v6 > 0.f ? v6 : 0.f; v7 = v7 > 0.f ? v7 : 0.f;
        uint4 out;
        out.x = packbf(v0, v1); out.y = packbf(v2, v3);
        out.z = packbf(v4, v5); out.w = packbf(v6, v7);
        outb[idx] = out;
    } else {
        outf[2 * idx]     = make_float4(v0, v1, v2, v3);
        outf[2 * idx + 1] = make_float4(v4, v5, v6, v7);
    }
}

extern "C" void kernel_launch(void* const* d_in, const int* in_sizes, int n_in,
                              void* d_out, int out_size, void* d_ws, size_t ws_size,
                              hipStream_t stream) {
    const int* x  = (const int*)d_in[0];
    const int* ei = (const int*)d_in[1];
    const int* ea = (const int*)d_in[2];
    // d_in[3] = batch (unused)
    const float* xe1 = (const float*)d_in[4];
    const float* xe2 = (const float*)d_in[5];
    const float* e1  = (const float*)d_in[6];   // [2][7][128]
    const float* e2  = (const float*)d_in[7];   // [2][3][128]
    const float* W1  = (const float*)d_in[8];   // [2][128][256]
    const float* b1  = (const float*)d_in[9];   // [2][256]
    const float* W2  = (const float*)d_in[10];  // [2][256][128]
    const float* b2  = (const float*)d_in[11];  // [2][128]
    const float* gm  = (const float*)d_in[12];  // [2][128]
    const float* bt  = (const float*)d_in[13];  // [2][128]

    char* ws = (char*)d_ws;
    size_t off = 0;
    auto take = [&](size_t bytes) -> char* {
        char* p = ws + off;
        off = (off + bytes + 255) & ~(size_t)255;
        return p;
    };
    unsigned int* h_buf = (unsigned int*)take((size_t)(N_NODES + 1) * 64 * 4); // +1 zero row
    unsigned int* aggb  = (unsigned int*)take((size_t)NPAD * 64 * 4);          // agg, then h2
    unsigned short* w1t = (unsigned short*)take((size_t)2 * 32768 * 2);
    unsigned short* w2t = (unsigned short*)take((size_t)2 * 32768 * 2);
    // combined zero-init region: deg[50000] | bnsum[512] | bmeta[32]
    int* zbuf   = (int*)take((size_t)(N_NODES + 512 + 32) * 4);
    int* deg    = zbuf;
    float* bnsum = (float*)(zbuf + N_NODES);            // [2][256]
    int* bmeta  = zbuf + N_NODES + 512;                 // bcnt[8], bcur[8], gcur[1]
    int* offs   = (int*)take((size_t)(N_NODES + 1) * 4);
    int* cursor = (int*)take((size_t)N_NODES * 4);
    int* keys   = (int*)take((size_t)(N_EDGES + N_NODES * 16) * 4);
    int* keyv   = (int*)take((size_t)N_EDGES * 4);
    int* perm   = (int*)take((size_t)N_NODES * 4);
    int* bcnt = bmeta, *bcur = bmeta + 8, *gcur = bmeta + 16;

    hipMemsetAsync(zbuf, 0, (size_t)(N_NODES + 512 + 32) * 4, stream);
    k_prep<<<((N_NODES + 1) * 64 + 255) / 256, 256, 0, stream>>>(x, xe1, xe2, h_buf,
                                                                 W1, W2, w1t, w2t, deg,
                                                                 ei, ea, keyv);
    k_alloc<<<PBLK, 256, 0, stream>>>(deg, gcur, offs, cursor, keys, bcnt);
    k_fill<<<8 * NCHUNKS, 256, 0, stream>>>(ei + N_EDGES, keyv, cursor, keys,
                                            deg, bcnt, bcur, perm);

    for (int l = 0; l < 2; ++l) {
        k_agg<<<NPAD / 16, 256, 0, stream>>>(h_buf, offs, deg, keys, perm,
                                             e1 + l * 896, e2 + l * 384, aggb);
        k_mlp<<<MBLK, 256, 0, stream>>>((unsigned short*)aggb, w1t + l * 32768, b1 + l * 256,
                                        w2t + l * 32768, b2 + l * 128, bnsum + l * 256);
        k_bnnorm<<<(N_NODES * 16 + 255) / 256, 256, 0, stream>>>((const uint4*)aggb, bnsum + l * 256,
                                                                 gm + l * 128, bt + l * 128,
                                                                 (uint4*)h_buf, (float4*)d_out, l);
    }
}